// Round 3
// baseline (271.141 us; speedup 1.0000x reference)
//
#include <hip/hip_runtime.h>

namespace {
constexpr int N_ = 8, C_ = 32, H_ = 256, W_ = 512, DISP_ = 25;
constexpr int CH_STRIDE = H_ * W_;  // elements between channels
}

// Disparity-split kernel: 256 threads/block = one (n,h) row.
//   t = tid & 127 -> 4 output columns (w0 = 4t)
//   g = tid >> 7  -> disparity group: g=0 handles i in [0,13), g=1 in [13,25)
// Each thread: acc[13][4] (52 regs), 16-col y window (4 float4), so total
// ~110 VGPRs -> 4 waves/SIMD (vs 2 before). Double-buffered channel prefetch.
//
// y window for group g starts at w0 - 12*g:
//   g=0: j = w0+cw+12-i, i in [0,12]  -> j in [w0,   w0+15]
//   g=1: j = w0+cw+12-i, i in [13,24] -> j in [w0-12, w0+2]
// ywin[m] = y[w0 - 12*g + m]; m = cw + 12 - g - il  (il = i - 13*g), all
// compile-time indices. Clamped windows are fully OOB (start multiple of 4)
// and only feed epilogue-zeroed outputs.
template <int G>
__device__ __forceinline__ void disp_body(const float* __restrict__ xp,
                                          const float* __restrict__ yp,
                                          float* __restrict__ op,
                                          const int* yoff, int w0) {
  constexpr int NI = 13 - G;  // 13 or 12 disparities

  float acc[NI][4];
#pragma unroll
  for (int il = 0; il < NI; ++il)
#pragma unroll
    for (int cw = 0; cw < 4; ++cw) acc[il][cw] = 0.0f;

  float4 xv0, xv1;
  float4 yv0[4], yv1[4];

#define LOADP(XV, YV, c)                                                   \
  do {                                                                     \
    const float* xq = xp + (size_t)(c)*CH_STRIDE;                          \
    const float* yq = yp + (size_t)(c)*CH_STRIDE;                          \
    XV = *reinterpret_cast<const float4*>(xq);                             \
    _Pragma("unroll") for (int k = 0; k < 4; ++k) YV[k] =                  \
        *reinterpret_cast<const float4*>(yq + yoff[k]);                    \
  } while (0)

#define COMPUTE(XV, YV)                                                    \
  do {                                                                     \
    float ywin[16];                                                        \
    _Pragma("unroll") for (int k = 0; k < 4; ++k) {                        \
      ywin[4 * k + 0] = YV[k].x;                                           \
      ywin[4 * k + 1] = YV[k].y;                                           \
      ywin[4 * k + 2] = YV[k].z;                                           \
      ywin[4 * k + 3] = YV[k].w;                                           \
    }                                                                      \
    const float xs0 = XV.x, xs1 = XV.y, xs2 = XV.z, xs3 = XV.w;            \
    _Pragma("unroll") for (int il = 0; il < NI; ++il) {                    \
      acc[il][0] += fabsf(xs0 - ywin[0 + 12 - G - il]);                    \
      acc[il][1] += fabsf(xs1 - ywin[1 + 12 - G - il]);                    \
      acc[il][2] += fabsf(xs2 - ywin[2 + 12 - G - il]);                    \
      acc[il][3] += fabsf(xs3 - ywin[3 + 12 - G - il]);                    \
    }                                                                      \
  } while (0)

  LOADP(xv0, yv0, 0);
#pragma unroll 1
  for (int c = 0; c < C_ - 2; c += 2) {
    LOADP(xv1, yv1, c + 1);
    COMPUTE(xv0, yv0);
    LOADP(xv0, yv0, c + 2);
    COMPUTE(xv1, yv1);
  }
  LOADP(xv1, yv1, C_ - 1);
  COMPUTE(xv0, yv0);
  COMPUTE(xv1, yv1);

#undef LOADP
#undef COMPUTE

  // Epilogue: zero out-of-overlap (w,i) pairs, coalesced float4 stores.
#pragma unroll
  for (int il = 0; il < NI; ++il) {
    const int i = 13 * G + il;
    const int j0 = w0 - i + 12;  // y column used by cw=0
    float4 v;
    v.x = ((unsigned)(j0 + 0) < (unsigned)W_) ? acc[il][0] : 0.0f;
    v.y = ((unsigned)(j0 + 1) < (unsigned)W_) ? acc[il][1] : 0.0f;
    v.z = ((unsigned)(j0 + 2) < (unsigned)W_) ? acc[il][2] : 0.0f;
    v.w = ((unsigned)(j0 + 3) < (unsigned)W_) ? acc[il][3] : 0.0f;
    *reinterpret_cast<float4*>(op + (size_t)i * CH_STRIDE) = v;
  }
}

__global__ __launch_bounds__(256, 4) void rescost_kernel(
    const float* __restrict__ x, const float* __restrict__ y,
    float* __restrict__ out) {
  const int tid = threadIdx.x;
  const int t = tid & 127;   // column group
  const int g = tid >> 7;    // disparity group (wave-uniform)
  const int r = blockIdx.x;  // row in [0, N*H)
  const int n = r >> 8;      // H = 256
  const int h = r & (H_ - 1);
  const int w0 = t << 2;

  // 4 clamped 16B-aligned y-window offsets starting at w0 - 12*g.
  int yoff[4];
  const int ybase = w0 - 12 * g;
#pragma unroll
  for (int k = 0; k < 4; ++k) {
    int idx = ybase + 4 * k;
    idx = idx < 0 ? 0 : idx;
    idx = idx > (W_ - 4) ? (W_ - 4) : idx;
    yoff[k] = idx;
  }

  const size_t row_base = ((size_t)n * C_ * H_ + (size_t)h) * W_;
  const float* xp = x + row_base + w0;
  const float* yp = y + row_base;
  float* op = out + ((size_t)n * DISP_ * H_ + (size_t)h) * W_ + w0;

  if (g == 0)
    disp_body<0>(xp, yp, op, yoff, w0);
  else
    disp_body<1>(xp, yp, op, yoff, w0);
}

extern "C" void kernel_launch(void* const* d_in, const int* in_sizes, int n_in,
                              void* d_out, int out_size, void* d_ws, size_t ws_size,
                              hipStream_t stream) {
  const float* x = (const float*)d_in[0];
  const float* y = (const float*)d_in[1];
  float* out = (float*)d_out;
  dim3 grid(N_ * H_);  // one (n,h) row per block
  dim3 block(256);
  hipLaunchKernelGGL(rescost_kernel, grid, block, 0, stream, x, y, out);
}

// Round 4
// 94.160 us; speedup vs baseline: 2.8796x; 2.8796x over previous
//
#include <hip/hip_runtime.h>

namespace {
constexpr int N_ = 8, C_ = 32, H_ = 256, W_ = 512, DISP_ = 25;
constexpr int CH_STRIDE = H_ * W_;  // elements between channels
}

// Disparity-split kernel: 256 threads/block = one (n,h) row.
//   t = tid & 127 -> 4 output columns (w0 = 4t)
//   g = tid >> 7  -> disparity group: g=0 handles i in [0,13), g=1 in [13,25)
// Per-thread state: acc[13][4] (52) + yv[4] float4 (16) + xv (4) + addr (~18)
// ~= 90 VGPRs -> ~5 waves/SIMD. NO double-buffer (round-3 post-mortem: dbuf
// blew the 128-reg cap under launch_bounds(256,4) and spilled to scratch,
// WRITE_SIZE 539 MB). TLP at 5 waves/SIMD hides load latency instead.
//
// ywin[m] = y[w0 - 12*g + m]; compute index m = cw + 12 - G - il
// (il = i - 13*G), all compile-time. Clamped windows are fully OOB (window
// base is a multiple of 4) and only feed epilogue-zeroed outputs.
template <int G>
__device__ __forceinline__ void disp_body(const float* __restrict__ xp,
                                          const float* __restrict__ yp,
                                          float* __restrict__ op,
                                          const int* yoff, int w0) {
  constexpr int NI = 13 - G;  // 13 or 12 disparities

  float acc[NI][4];
#pragma unroll
  for (int il = 0; il < NI; ++il)
#pragma unroll
    for (int cw = 0; cw < 4; ++cw) acc[il][cw] = 0.0f;

#pragma unroll 1
  for (int c = 0; c < C_; ++c) {
    // Issue all 5 loads up front; compiler inserts counted waitcnt.
    float4 yv[4];
#pragma unroll
    for (int k = 0; k < 4; ++k)
      yv[k] = *reinterpret_cast<const float4*>(yp + yoff[k]);
    const float4 xv = *reinterpret_cast<const float4*>(xp);

    const float xs[4] = {xv.x, xv.y, xv.z, xv.w};
    // ywin[m] == component (m&3) of yv[m>>2]; m is compile-time below.
    const float ywin[16] = {yv[0].x, yv[0].y, yv[0].z, yv[0].w,
                            yv[1].x, yv[1].y, yv[1].z, yv[1].w,
                            yv[2].x, yv[2].y, yv[2].z, yv[2].w,
                            yv[3].x, yv[3].y, yv[3].z, yv[3].w};

#pragma unroll
    for (int il = 0; il < NI; ++il) {
#pragma unroll
      for (int cw = 0; cw < 4; ++cw) {
        acc[il][cw] += fabsf(xs[cw] - ywin[cw + 12 - G - il]);
      }
    }

    xp += CH_STRIDE;
    yp += CH_STRIDE;
  }

  // Epilogue: zero out-of-overlap (w,i) pairs, coalesced float4 stores.
#pragma unroll
  for (int il = 0; il < NI; ++il) {
    const int i = 13 * G + il;
    const int j0 = w0 - i + 12;  // y column used by cw=0
    float4 v;
    v.x = ((unsigned)(j0 + 0) < (unsigned)W_) ? acc[il][0] : 0.0f;
    v.y = ((unsigned)(j0 + 1) < (unsigned)W_) ? acc[il][1] : 0.0f;
    v.z = ((unsigned)(j0 + 2) < (unsigned)W_) ? acc[il][2] : 0.0f;
    v.w = ((unsigned)(j0 + 3) < (unsigned)W_) ? acc[il][3] : 0.0f;
    *reinterpret_cast<float4*>(op + (size_t)i * CH_STRIDE) = v;
  }
}

__global__ __launch_bounds__(256, 4) void rescost_kernel(
    const float* __restrict__ x, const float* __restrict__ y,
    float* __restrict__ out) {
  const int tid = threadIdx.x;
  const int t = tid & 127;   // column group
  const int g = tid >> 7;    // disparity group (wave-uniform)
  const int r = blockIdx.x;  // row in [0, N*H)
  const int n = r >> 8;      // H = 256
  const int h = r & (H_ - 1);
  const int w0 = t << 2;

  // 4 clamped 16B-aligned y-window offsets starting at w0 - 12*g.
  int yoff[4];
  const int ybase = w0 - 12 * g;
#pragma unroll
  for (int k = 0; k < 4; ++k) {
    int idx = ybase + 4 * k;
    idx = idx < 0 ? 0 : idx;
    idx = idx > (W_ - 4) ? (W_ - 4) : idx;
    yoff[k] = idx;
  }

  const size_t row_base = ((size_t)n * C_ * H_ + (size_t)h) * W_;
  const float* xp = x + row_base + w0;
  const float* yp = y + row_base;
  float* op = out + ((size_t)n * DISP_ * H_ + (size_t)h) * W_ + w0;

  if (g == 0)
    disp_body<0>(xp, yp, op, yoff, w0);
  else
    disp_body<1>(xp, yp, op, yoff, w0);
}

extern "C" void kernel_launch(void* const* d_in, const int* in_sizes, int n_in,
                              void* d_out, int out_size, void* d_ws, size_t ws_size,
                              hipStream_t stream) {
  const float* x = (const float*)d_in[0];
  const float* y = (const float*)d_in[1];
  float* out = (float*)d_out;
  dim3 grid(N_ * H_);  // one (n,h) row per block
  dim3 block(256);
  hipLaunchKernelGGL(rescost_kernel, grid, block, 0, stream, x, y, out);
}